// Round 3
// baseline (2005.090 us; speedup 1.0000x reference)
//
#include <hip/hip_runtime.h>
#include <cstdint>
#include <cstddef>

typedef short  short8  __attribute__((ext_vector_type(8)));
typedef float  float4v __attribute__((ext_vector_type(4)));

#define MFMA_B16(a,b,c) __builtin_amdgcn_mfma_f32_16x16x32_bf16(a,b,c,0,0,0)

static constexpr int B_  = 512;
static constexpr int T_  = 256;
static constexpr int DIN = 32;
static constexpr int H_  = 128;
static constexpr int TGT = 64;

// ---- workspace layout (bytes) ----
static constexpr size_t OFF_XFRAG = 0;                          // 8,388,608
static constexpr size_t OFF_EW0   = 8388608;                    // 163,840
static constexpr size_t OFF_EW1   = OFF_EW0 + 163840;           // 262,144
static constexpr size_t OFF_DW0   = OFF_EW1 + 262144;           // 163,840
static constexpr size_t OFF_DW1   = OFF_DW0 + 163840;           // 262,144
static constexpr size_t OFF_LIN   = OFF_DW1 + 262144;           // 8,192
static constexpr size_t OFF_BIAS  = OFF_LIN + 8192;             // 8,320
static constexpr size_t OFF_CTRL  = ((OFF_BIAS + 8320 + 255)/256)*256;  // 32 pairs * 256 B
static constexpr size_t OFF_RING  = OFF_CTRL + 8192;            // 32 pairs * 4 slots * 4096 B
static constexpr size_t OFF_OUTF  = OFF_RING + 524288;          // 32 pairs * 1024 B
static constexpr size_t WS_NEED   = OFF_OUTF + 32768;           // ~9.37 MB

__device__ __forceinline__ short f2bf(float f){
  unsigned u = __float_as_uint(f);
  unsigned r = (u + 0x7fffu + ((u>>16)&1u)) >> 16;   // RNE
  return (short)(r & 0xffffu);
}
__device__ __forceinline__ float fast_sigm(float x){
  float e = __expf(-x);
  return __builtin_amdgcn_rcpf(1.f + e);
}
__device__ __forceinline__ float fast_tanh(float x){
  float e = __expf(-2.f*x);                 // tanh = 2*sigm(2x)-1
  return __builtin_amdgcn_rcpf(1.f + e)*2.f - 1.f;
}

__device__ __forceinline__ int ld_acq(int* p){ return __hip_atomic_load(p, __ATOMIC_ACQUIRE, __HIP_MEMORY_SCOPE_AGENT); }
__device__ __forceinline__ int ld_rlx(int* p){ return __hip_atomic_load(p, __ATOMIC_RELAXED, __HIP_MEMORY_SCOPE_AGENT); }
__device__ __forceinline__ void st_rel(int* p, int v){ __hip_atomic_store(p, v, __ATOMIC_RELEASE, __HIP_MEMORY_SCOPE_AGENT); }
__device__ __forceinline__ void st_rlx(int* p, int v){ __hip_atomic_store(p, v, __ATOMIC_RELAXED, __HIP_MEMORY_SCOPE_AGENT); }

// ---------------- prep: x -> bf16 A-fragment tiles ----------------
__global__ void prep_x_kernel(const float* __restrict__ x, short8* __restrict__ xfrag){
  int i = blockIdx.x*256 + threadIdx.x;           // 32*256*64 entries
  if (i >= 32*256*64) return;
  int l    = i & 63;
  int t    = (i >> 6) & 255;
  int bblk = i >> 14;
  int b    = bblk*16 + (l & 15);
  const float* src = x + ((size_t)(b*T_ + t))*DIN + ((l>>4)*8);
  short8 v;
  #pragma unroll
  for (int j=0;j<8;j++) v[j] = f2bf(src[j]);
  xfrag[i] = v;
}

// ---------------- prep: weights -> bf16 B-fragment tiles ----------------
__device__ __forceinline__ void pack160(short8* __restrict__ dst,
                                        const float* __restrict__ Wih,   // (512,32)
                                        const float* __restrict__ Whh,   // (512,128)
                                        int e){
  int nt = e/320; int r = e%320; int kb = r/64; int l = r%64;
  int n  = nt*16 + (l&15);
  short8 v;
  #pragma unroll
  for (int j=0;j<8;j++){
    int k = kb*32 + (l>>4)*8 + j;
    float f = (k < 32) ? Wih[n*32 + k] : Whh[n*128 + (k-32)];
    v[j] = f2bf(f);
  }
  dst[e] = v;
}
__device__ __forceinline__ void pack256(short8* __restrict__ dst,
                                        const float* __restrict__ Wih,   // (512,128)
                                        const float* __restrict__ Whh,   // (512,128)
                                        int e){
  int nt = e/512; int r = e%512; int kb = r/64; int l = r%64;
  int n  = nt*16 + (l&15);
  short8 v;
  #pragma unroll
  for (int j=0;j<8;j++){
    int k = kb*32 + (l>>4)*8 + j;
    float f = (k < 128) ? Wih[n*128 + k] : Whh[n*128 + (k-128)];
    v[j] = f2bf(f);
  }
  dst[e] = v;
}

__global__ void prep_w_kernel(
    const float* __restrict__ eWih0, const float* __restrict__ eWhh0,
    const float* __restrict__ eWih1, const float* __restrict__ eWhh1,
    const float* __restrict__ dWih0, const float* __restrict__ dWhh0,
    const float* __restrict__ dWih1, const float* __restrict__ dWhh1,
    const float* __restrict__ linW,
    const float* __restrict__ eb0a, const float* __restrict__ eb0b,
    const float* __restrict__ eb1a, const float* __restrict__ eb1b,
    const float* __restrict__ db0a, const float* __restrict__ db0b,
    const float* __restrict__ db1a, const float* __restrict__ db1b,
    const float* __restrict__ linb,
    short8* __restrict__ encW0, short8* __restrict__ encW1,
    short8* __restrict__ decW0, short8* __restrict__ decW1,
    short8* __restrict__ linT,  float* __restrict__ biases)
{
  int i = blockIdx.x*256 + threadIdx.x;
  if (i < 10240)       { pack160(encW0, eWih0, eWhh0, i); }
  else if (i < 26624)  { pack256(encW1, eWih1, eWhh1, i-10240); }
  else if (i < 36864)  { pack160(decW0, dWih0, dWhh0, i-26624); }
  else if (i < 53248)  { pack256(decW1, dWih1, dWhh1, i-36864); }
  else if (i < 53760)  {
    int e = i - 53248;                       // lin: 2nt * 4kb * 64
    int nt = e/256; int r = e%256; int kb = r/64; int l = r%64;
    int n = nt*16 + (l&15);
    short8 v;
    #pragma unroll
    for (int j=0;j<8;j++){
      int k = kb*32 + (l>>4)*8 + j;          // k < 128
      v[j] = f2bf(linW[n*128 + k]);
    }
    linT[e] = v;
  }
  else if (i < 55840)  {
    int e = i - 53760;                       // 2080 bias entries
    float v;
    if      (e < 512)  v = eb0a[e]       + eb0b[e];
    else if (e < 1024) v = eb1a[e-512]   + eb1b[e-512];
    else if (e < 1536) v = db0a[e-1024]  + db0b[e-1024];
    else if (e < 2048) v = db1a[e-1536]  + db1b[e-1536];
    else               v = linb[e-2048];
    biases[e] = v;
  }
}

__global__ void zero_ctrl_kernel(int* __restrict__ ctrl){
  int i = blockIdx.x*256 + threadIdx.x;
  if (i < 2048) ctrl[i] = 0;
}

// ---------------- main layer-pipelined kernel ----------------
// 64 blocks = 32 pairs. Pair p: A-block (layer 0) + B-block (layer 1 + proj).
// Pair indices (i, i+8) -> same XCD under %8 round-robin (heuristic only).
// A publishes h0(t) A-fragments into a 4-slot L2 ring with release/acquire
// flags; B lags one step. Decoder: B publishes out(td) frags back to A.
__global__ __launch_bounds__(512, 2) void lstm_pipe_kernel(
    const short8* __restrict__ xfrag,
    const short8* __restrict__ encW0, const short8* __restrict__ encW1,
    const short8* __restrict__ decW0, const short8* __restrict__ decW1,
    const short8* __restrict__ linT,  const float* __restrict__ biases,
    int* __restrict__ ctrl, short8* __restrict__ h0ring, short8* __restrict__ outfrg,
    float* __restrict__ out)
{
  __shared__ __align__(16) short Abuf[16][264];   // [row][128*2 parity + pad]
  __shared__ __align__(16) short projbuf[16][40];

  const int tid  = threadIdx.x;
  const int w    = tid >> 6;
  const int l    = tid & 63;
  const int col  = l & 15;
  const int lq   = l >> 4;
  const int pid  = (blockIdx.x & 7) | ((blockIdx.x >> 4) << 3);
  const bool isB = (blockIdx.x >> 3) & 1;

  int* aflag = ctrl + (size_t)pid*64;
  int* bprog = aflag + 16;
  int* oflag = aflag + 32;
  short8* ring = h0ring + (size_t)pid*4*256;     // 4 slots x 256 short8
  short8* ofr  = outfrg + (size_t)pid*64;

  for (int i = tid; i < 16*264; i += 512) ((short*)Abuf)[i] = 0;

  if (!isB){
    // ================= A: layer 0 =================
    short8 W0r[4][5];
    #pragma unroll
    for (int i=0;i<4;i++)
      #pragma unroll
      for (int kb=0;kb<5;kb++) W0r[i][kb] = encW0[(size_t)(8*i+w)*320 + (size_t)kb*64 + l];
    float bs0[4];
    #pragma unroll
    for (int i=0;i<4;i++) bs0[i] = biases[(8*i+w)*16 + col];
    float c0[4] = {0.f,0.f,0.f,0.f};

    const short8* xf = xfrag + (size_t)pid*T_*64 + l;
    short8 a0 = xf[0];
    __syncthreads();

    #pragma unroll 2
    for (int t = 0; t < T_; t++){
      const int h0r = (t & 1) * 128;
      const int h0w = 128 - h0r;
      short8 ah[4];
      #pragma unroll
      for (int kb=0;kb<4;kb++) ah[kb] = *(const short8*)&Abuf[col][h0r + kb*32 + lq*8];
      float4v acc[4];
      #pragma unroll
      for (int i=0;i<4;i++){
        float4v a = {bs0[i],bs0[i],bs0[i],bs0[i]};
        a = MFMA_B16(a0, W0r[i][0], a);
        #pragma unroll
        for (int kb=0;kb<4;kb++) a = MFMA_B16(ah[kb], W0r[i][kb+1], a);
        acc[i] = a;
      }
      short8 a0n = xf[(size_t)((t+1 < T_) ? t+1 : t)*64];
      #pragma unroll
      for (int q=0;q<4;q++){
        float cc = fast_sigm(acc[1][q])*c0[q] + fast_sigm(acc[0][q])*fast_tanh(acc[2][q]);
        c0[q] = cc;
        Abuf[lq*4+q][h0w + 16*w + col] = f2bf(fast_sigm(acc[3][q])*fast_tanh(cc));
      }
      a0 = a0n;
      __syncthreads();
      if (w < 4){
        if (t >= 4){ while (ld_rlx(bprog) < t-3) __builtin_amdgcn_s_sleep(1); }
        short8 v = *(const short8*)&Abuf[col][h0w + w*32 + lq*8];
        ring[(size_t)(t&3)*256 + w*64 + l] = v;
      }
      __syncthreads();
      if (tid == 0) st_rel(aflag, t+1);
    }

    // ---- decoder weights ----
    #pragma unroll
    for (int i=0;i<4;i++){
      #pragma unroll
      for (int kb=0;kb<5;kb++) W0r[i][kb] = decW0[(size_t)(8*i+w)*320 + (size_t)kb*64 + l];
      bs0[i] = biases[1024 + (8*i+w)*16 + col];
    }
    short8 a0d = xf[(size_t)(T_-1)*64];

    #pragma unroll 2
    for (int td = 0; td < TGT; td++){
      const int t = T_ + td;
      if (td >= 1){
        while (ld_acq(oflag) < td) __builtin_amdgcn_s_sleep(1);
        a0d = ofr[l];
      }
      const int h0r = (t & 1) * 128;
      const int h0w = 128 - h0r;
      short8 ah[4];
      #pragma unroll
      for (int kb=0;kb<4;kb++) ah[kb] = *(const short8*)&Abuf[col][h0r + kb*32 + lq*8];
      float4v acc[4];
      #pragma unroll
      for (int i=0;i<4;i++){
        float4v a = {bs0[i],bs0[i],bs0[i],bs0[i]};
        a = MFMA_B16(a0d, W0r[i][0], a);
        #pragma unroll
        for (int kb=0;kb<4;kb++) a = MFMA_B16(ah[kb], W0r[i][kb+1], a);
        acc[i] = a;
      }
      #pragma unroll
      for (int q=0;q<4;q++){
        float cc = fast_sigm(acc[1][q])*c0[q] + fast_sigm(acc[0][q])*fast_tanh(acc[2][q]);
        c0[q] = cc;
        Abuf[lq*4+q][h0w + 16*w + col] = f2bf(fast_sigm(acc[3][q])*fast_tanh(cc));
      }
      __syncthreads();
      if (w < 4){
        while (ld_rlx(bprog) < t-3) __builtin_amdgcn_s_sleep(1);
        short8 v = *(const short8*)&Abuf[col][h0w + w*32 + lq*8];
        ring[(size_t)(t&3)*256 + w*64 + l] = v;
      }
      __syncthreads();
      if (tid == 0) st_rel(aflag, t+1);
    }
  } else {
    // ================= B: layer 1 + projection =================
    short8 W1r[4][8];
    #pragma unroll
    for (int i=0;i<4;i++)
      #pragma unroll
      for (int kb=0;kb<8;kb++) W1r[i][kb] = encW1[(size_t)(8*i+w)*512 + (size_t)kb*64 + l];
    float bs1[4];
    #pragma unroll
    for (int i=0;i<4;i++) bs1[i] = biases[512 + (8*i+w)*16 + col];
    float c1[4] = {0.f,0.f,0.f,0.f};
    __syncthreads();

    #pragma unroll 2
    for (int t = 0; t < T_; t++){
      while (ld_acq(aflag) < t+1) __builtin_amdgcn_s_sleep(1);
      short8 g0[4];
      #pragma unroll
      for (int kb=0;kb<4;kb++) g0[kb] = ring[(size_t)(t&3)*256 + kb*64 + l];
      const int h1r = (t & 1) * 128;
      const int h1w = 128 - h1r;
      short8 a1[4];
      #pragma unroll
      for (int kb=0;kb<4;kb++) a1[kb] = *(const short8*)&Abuf[col][h1r + kb*32 + lq*8];
      float4v acc[4];
      #pragma unroll
      for (int i=0;i<4;i++){
        float4v a = {bs1[i],bs1[i],bs1[i],bs1[i]};
        #pragma unroll
        for (int kb=0;kb<4;kb++) a = MFMA_B16(a1[kb], W1r[i][4+kb], a);   // LDS half first
        #pragma unroll
        for (int kb=0;kb<4;kb++) a = MFMA_B16(g0[kb], W1r[i][kb], a);    // hides global latency
        acc[i] = a;
      }
      #pragma unroll
      for (int q=0;q<4;q++){
        float cc = fast_sigm(acc[1][q])*c1[q] + fast_sigm(acc[0][q])*fast_tanh(acc[2][q]);
        c1[q] = cc;
        Abuf[lq*4+q][h1w + 16*w + col] = f2bf(fast_sigm(acc[3][q])*fast_tanh(cc));
      }
      __syncthreads();
      if (tid == 0) st_rlx(bprog, t+1);
    }

    // ---- decoder weights ----
    #pragma unroll
    for (int i=0;i<4;i++){
      #pragma unroll
      for (int kb=0;kb<8;kb++) W1r[i][kb] = decW1[(size_t)(8*i+w)*512 + (size_t)kb*64 + l];
      bs1[i] = biases[1536 + (8*i+w)*16 + col];
    }
    short8 WLr[4];
    float blin = 0.f;
    if (w < 2){
      #pragma unroll
      for (int kb=0;kb<4;kb++) WLr[kb] = linT[(size_t)(w*4+kb)*64 + l];
      blin = biases[2048 + w*16 + col];
    }

    #pragma unroll 2
    for (int td = 0; td < TGT; td++){
      const int t = T_ + td;
      while (ld_acq(aflag) < t+1) __builtin_amdgcn_s_sleep(1);
      short8 g0[4];
      #pragma unroll
      for (int kb=0;kb<4;kb++) g0[kb] = ring[(size_t)(t&3)*256 + kb*64 + l];
      const int h1r = (t & 1) * 128;
      const int h1w = 128 - h1r;
      short8 a1[4];
      #pragma unroll
      for (int kb=0;kb<4;kb++) a1[kb] = *(const short8*)&Abuf[col][h1r + kb*32 + lq*8];
      float4v acc[4];
      #pragma unroll
      for (int i=0;i<4;i++){
        float4v a = {bs1[i],bs1[i],bs1[i],bs1[i]};
        #pragma unroll
        for (int kb=0;kb<4;kb++) a = MFMA_B16(a1[kb], W1r[i][4+kb], a);
        #pragma unroll
        for (int kb=0;kb<4;kb++) a = MFMA_B16(g0[kb], W1r[i][kb], a);
        acc[i] = a;
      }
      #pragma unroll
      for (int q=0;q<4;q++){
        float cc = fast_sigm(acc[1][q])*c1[q] + fast_sigm(acc[0][q])*fast_tanh(acc[2][q]);
        c1[q] = cc;
        Abuf[lq*4+q][h1w + 16*w + col] = f2bf(fast_sigm(acc[3][q])*fast_tanh(cc));
      }
      __syncthreads();
      if (tid == 0) st_rlx(bprog, t+1);
      // projection
      if (w < 2){
        short8 hf[4];
        #pragma unroll
        for (int kb=0;kb<4;kb++) hf[kb] = *(const short8*)&Abuf[col][h1w + kb*32 + lq*8];
        float4v a = {blin,blin,blin,blin};
        #pragma unroll
        for (int kb=0;kb<4;kb++) a = MFMA_B16(hf[kb], WLr[kb], a);
        #pragma unroll
        for (int q=0;q<4;q++){
          float v = a[q];
          int b = pid*16 + lq*4 + q;
          out[((size_t)b*TGT + td)*DIN + (w*16 + col)] = v;
          projbuf[lq*4+q][w*16 + col] = f2bf(v);
        }
      }
      __syncthreads();
      if (w == 0){
        short8 v = *(const short8*)&projbuf[col][lq*8];
        ofr[l] = v;
      }
      __syncthreads();
      if (tid == 0) st_rel(oflag, td+1);
    }
  }
}

// ---------------- host ----------------
extern "C" void kernel_launch(void* const* d_in, const int* in_sizes, int n_in,
                              void* d_out, int out_size, void* d_ws, size_t ws_size,
                              hipStream_t stream) {
  const float* x      = (const float*)d_in[0];
  const float* eWih0  = (const float*)d_in[2];
  const float* eWhh0  = (const float*)d_in[3];
  const float* eb0a   = (const float*)d_in[4];
  const float* eb0b   = (const float*)d_in[5];
  const float* eWih1  = (const float*)d_in[6];
  const float* eWhh1  = (const float*)d_in[7];
  const float* eb1a   = (const float*)d_in[8];
  const float* eb1b   = (const float*)d_in[9];
  const float* dWih0  = (const float*)d_in[10];
  const float* dWhh0  = (const float*)d_in[11];
  const float* db0a   = (const float*)d_in[12];
  const float* db0b   = (const float*)d_in[13];
  const float* dWih1  = (const float*)d_in[14];
  const float* dWhh1  = (const float*)d_in[15];
  const float* db1a   = (const float*)d_in[16];
  const float* db1b   = (const float*)d_in[17];
  const float* linW   = (const float*)d_in[18];
  const float* linb   = (const float*)d_in[19];

  char* ws = (char*)d_ws;
  short8* xfrag = (short8*)(ws + OFF_XFRAG);
  short8* encW0 = (short8*)(ws + OFF_EW0);
  short8* encW1 = (short8*)(ws + OFF_EW1);
  short8* decW0 = (short8*)(ws + OFF_DW0);
  short8* decW1 = (short8*)(ws + OFF_DW1);
  short8* linT  = (short8*)(ws + OFF_LIN);
  float*  biases= (float*)(ws + OFF_BIAS);
  int*    ctrl  = (int*)(ws + OFF_CTRL);
  short8* ring  = (short8*)(ws + OFF_RING);
  short8* outf  = (short8*)(ws + OFF_OUTF);

  prep_x_kernel<<<2048, 256, 0, stream>>>(x, xfrag);
  prep_w_kernel<<<219, 256, 0, stream>>>(
      eWih0,eWhh0,eWih1,eWhh1,dWih0,dWhh0,dWih1,dWhh1,linW,
      eb0a,eb0b,eb1a,eb1b,db0a,db0b,db1a,db1b,linb,
      encW0,encW1,decW0,decW1,linT,biases);
  zero_ctrl_kernel<<<8, 256, 0, stream>>>(ctrl);
  lstm_pipe_kernel<<<64, 512, 0, stream>>>(
      xfrag, encW0, encW1, decW0, decW1, linT, biases,
      ctrl, ring, outf, (float*)d_out);
}

// Round 4
// 1209.788 us; speedup vs baseline: 1.6574x; 1.6574x over previous
//
#include <hip/hip_runtime.h>
#include <cstdint>
#include <cstddef>

typedef short  short8  __attribute__((ext_vector_type(8)));
typedef float  float4v __attribute__((ext_vector_type(4)));

#define MFMA_B16(a,b,c) __builtin_amdgcn_mfma_f32_16x16x32_bf16(a,b,c,0,0,0)

static constexpr int B_  = 512;
static constexpr int T_  = 256;
static constexpr int DIN = 32;
static constexpr int H_  = 128;
static constexpr int TGT = 64;

// ---- workspace layout (bytes) ----
static constexpr size_t OFF_XFRAG = 0;                          // 8,388,608
static constexpr size_t OFF_EW0   = 8388608;                    // 163,840
static constexpr size_t OFF_EW1   = OFF_EW0 + 163840;           // 262,144
static constexpr size_t OFF_DW0   = OFF_EW1 + 262144;           // 163,840
static constexpr size_t OFF_DW1   = OFF_DW0 + 163840;           // 262,144
static constexpr size_t OFF_LIN   = OFF_DW1 + 262144;           // 8,192
static constexpr size_t OFF_BIAS  = OFF_LIN + 8192;             // 2080 floats
static constexpr size_t WS_NEED   = OFF_BIAS + 8320;

__device__ __forceinline__ short f2bf(float f){
  unsigned u = __float_as_uint(f);
  unsigned r = (u + 0x7fffu + ((u>>16)&1u)) >> 16;   // RNE
  return (short)(r & 0xffffu);
}
__device__ __forceinline__ float fast_sigm(float x){
  float e = __expf(-x);
  return __builtin_amdgcn_rcpf(1.f + e);
}
__device__ __forceinline__ float fast_tanh(float x){
  float e = __expf(-2.f*x);                 // tanh = 2*sigm(2x)-1
  return __builtin_amdgcn_rcpf(1.f + e)*2.f - 1.f;
}

// ---------------- prep: x -> bf16 A-fragment tiles ----------------
__global__ void prep_x_kernel(const float* __restrict__ x, short8* __restrict__ xfrag){
  int i = blockIdx.x*256 + threadIdx.x;           // 32*256*64 entries
  if (i >= 32*256*64) return;
  int l    = i & 63;
  int t    = (i >> 6) & 255;
  int bblk = i >> 14;
  int b    = bblk*16 + (l & 15);
  const float* src = x + ((size_t)(b*T_ + t))*DIN + ((l>>4)*8);
  short8 v;
  #pragma unroll
  for (int j=0;j<8;j++) v[j] = f2bf(src[j]);
  xfrag[i] = v;
}

// ---------------- prep: weights -> bf16 B-fragment tiles ----------------
__device__ __forceinline__ void pack160(short8* __restrict__ dst,
                                        const float* __restrict__ Wih,   // (512,32)
                                        const float* __restrict__ Whh,   // (512,128)
                                        int e){
  int nt = e/320; int r = e%320; int kb = r/64; int l = r%64;
  int n  = nt*16 + (l&15);
  short8 v;
  #pragma unroll
  for (int j=0;j<8;j++){
    int k = kb*32 + (l>>4)*8 + j;
    float f = (k < 32) ? Wih[n*32 + k] : Whh[n*128 + (k-32)];
    v[j] = f2bf(f);
  }
  dst[e] = v;
}
__device__ __forceinline__ void pack256(short8* __restrict__ dst,
                                        const float* __restrict__ Wih,   // (512,128)
                                        const float* __restrict__ Whh,   // (512,128)
                                        int e){
  int nt = e/512; int r = e%512; int kb = r/64; int l = r%64;
  int n  = nt*16 + (l&15);
  short8 v;
  #pragma unroll
  for (int j=0;j<8;j++){
    int k = kb*32 + (l>>4)*8 + j;
    float f = (k < 128) ? Wih[n*128 + k] : Whh[n*128 + (k-128)];
    v[j] = f2bf(f);
  }
  dst[e] = v;
}

__global__ void prep_w_kernel(
    const float* __restrict__ eWih0, const float* __restrict__ eWhh0,
    const float* __restrict__ eWih1, const float* __restrict__ eWhh1,
    const float* __restrict__ dWih0, const float* __restrict__ dWhh0,
    const float* __restrict__ dWih1, const float* __restrict__ dWhh1,
    const float* __restrict__ linW,
    const float* __restrict__ eb0a, const float* __restrict__ eb0b,
    const float* __restrict__ eb1a, const float* __restrict__ eb1b,
    const float* __restrict__ db0a, const float* __restrict__ db0b,
    const float* __restrict__ db1a, const float* __restrict__ db1b,
    const float* __restrict__ linb,
    short8* __restrict__ encW0, short8* __restrict__ encW1,
    short8* __restrict__ decW0, short8* __restrict__ decW1,
    short8* __restrict__ linT,  float* __restrict__ biases)
{
  int i = blockIdx.x*256 + threadIdx.x;
  if (i < 10240)       { pack160(encW0, eWih0, eWhh0, i); }
  else if (i < 26624)  { pack256(encW1, eWih1, eWhh1, i-10240); }
  else if (i < 36864)  { pack160(decW0, dWih0, dWhh0, i-26624); }
  else if (i < 53248)  { pack256(decW1, dWih1, dWhh1, i-36864); }
  else if (i < 53760)  {
    int e = i - 53248;                       // lin: 2nt * 4kb * 64
    int nt = e/256; int r = e%256; int kb = r/64; int l = r%64;
    int n = nt*16 + (l&15);
    short8 v;
    #pragma unroll
    for (int j=0;j<8;j++){
      int k = kb*32 + (l>>4)*8 + j;          // k < 128
      v[j] = f2bf(linW[n*128 + k]);
    }
    linT[e] = v;
  }
  else if (i < 55840)  {
    int e = i - 53760;                       // 2080 bias entries
    float v;
    if      (e < 512)  v = eb0a[e]       + eb0b[e];
    else if (e < 1024) v = eb1a[e-512]   + eb1b[e-512];
    else if (e < 1536) v = db0a[e-1024]  + db0b[e-1024];
    else if (e < 2048) v = db1a[e-1536]  + db1b[e-1536];
    else               v = linb[e-2048];
    biases[e] = v;
  }
}

// ---------------- main fused persistent kernel ----------------
// 32 blocks (16 batch rows each) x 512 threads (8 waves).
// Wave w owns gate n-tiles {w, 8+w, 16+w, 24+w} = i,f,g,o gates of hidden
// slice [16w,16w+16) -> activations consume the wave's OWN accumulators.
// Weights live in VGPRs (enc, then dec): 208 regs/wave of weights.
// __launch_bounds__(512,1): 2 waves/SIMD -> 512-VGPR cap -> NO SPILL.
// (Round 2 used (512,2) -> 256 cap -> ~72 spilled regs; grid is 32 blocks
//  on 256 CUs so >1 block/CU never happens anyway.)
__global__ __launch_bounds__(512, 1) void lstm_main_kernel(
    const short8* __restrict__ xfrag,
    const short8* __restrict__ encW0, const short8* __restrict__ encW1,
    const short8* __restrict__ decW0, const short8* __restrict__ decW1,
    const short8* __restrict__ linT,  const float* __restrict__ biases,
    float* __restrict__ out)
{
  __shared__ __align__(16) short Abuf[16][520];
  __shared__ __align__(16) short inpA[16][40];    // decoder input frame (32 cols)+pad

  const int tid  = threadIdx.x;
  const int w    = tid >> 6;
  const int l    = tid & 63;
  const int col  = l & 15;      // MFMA n (B,D) lane field / A m field
  const int lq   = l >> 4;
  const int bblk = blockIdx.x;

  for (int i = tid; i < 16*520; i += 512) ((short*)Abuf)[i] = 0;

  // ---- persistent weight registers (encoder first) ----
  short8 W0r[4][5];   // L0: n-tile 8i+w, kb<5  (k: 32 input + 128 h)
  short8 W1r[4][8];   // L1: n-tile 8i+w, kb<8  (k: 128 h0 + 128 h1)
  #pragma unroll
  for (int i=0;i<4;i++){
    #pragma unroll
    for (int kb=0;kb<5;kb++) W0r[i][kb] = encW0[(size_t)(8*i+w)*320 + (size_t)kb*64 + l];
    #pragma unroll
    for (int kb=0;kb<8;kb++) W1r[i][kb] = encW1[(size_t)(8*i+w)*512 + (size_t)kb*64 + l];
  }
  float bs0[4], bs1[4];
  #pragma unroll
  for (int i=0;i<4;i++){
    bs0[i] = biases[       (8*i+w)*16 + col];
    bs1[i] = biases[512 +  (8*i+w)*16 + col];
  }

  float c0[4] = {0.f,0.f,0.f,0.f};
  float c1[4] = {0.f,0.f,0.f,0.f};

  const short8* xf = xfrag + (size_t)bblk*T_*64 + l;
  short8 a0 = xf[0];
  __syncthreads();

  // ---------------- encoder: 256 steps ----------------
  #pragma unroll 2
  for (int t = 0; t < T_; t++){
    const int h0r = (t & 1) * 128;
    const int h0w = 128 - h0r;
    const int h1r = 256 + h0r;
    const int h1w = 256 + h0w;

    // ---- phase 1: layer 0 ----
    short8 ah[4];
    #pragma unroll
    for (int kb=0;kb<4;kb++) ah[kb] = *(const short8*)&Abuf[col][h0r + kb*32 + lq*8];
    float4v acc0[4];
    #pragma unroll
    for (int i=0;i<4;i++){
      float4v a = {bs0[i],bs0[i],bs0[i],bs0[i]};
      a = MFMA_B16(a0, W0r[i][0], a);
      #pragma unroll
      for (int kb=0;kb<4;kb++) a = MFMA_B16(ah[kb], W0r[i][kb+1], a);
      acc0[i] = a;
    }
    short8 a0n = xf[(size_t)((t+1 < T_) ? t+1 : t)*64];   // prefetch next frame
    #pragma unroll
    for (int q=0;q<4;q++){
      float cc = fast_sigm(acc0[1][q])*c0[q] + fast_sigm(acc0[0][q])*fast_tanh(acc0[2][q]);
      c0[q] = cc;
      Abuf[lq*4+q][h0w + 16*w + col] = f2bf(fast_sigm(acc0[3][q])*fast_tanh(cc));
    }
    a0 = a0n;
    __syncthreads();

    // ---- phase 2: layer 1 ----
    short8 a1[8];
    #pragma unroll
    for (int kb=0;kb<4;kb++) a1[kb]   = *(const short8*)&Abuf[col][h0w + kb*32 + lq*8];
    #pragma unroll
    for (int kb=0;kb<4;kb++) a1[4+kb] = *(const short8*)&Abuf[col][h1r + kb*32 + lq*8];
    float4v acc1[4];
    #pragma unroll
    for (int i=0;i<4;i++){
      float4v a = {bs1[i],bs1[i],bs1[i],bs1[i]};
      #pragma unroll
      for (int kb=0;kb<8;kb++) a = MFMA_B16(a1[kb], W1r[i][kb], a);
      acc1[i] = a;
    }
    #pragma unroll
    for (int q=0;q<4;q++){
      float cc = fast_sigm(acc1[1][q])*c1[q] + fast_sigm(acc1[0][q])*fast_tanh(acc1[2][q]);
      c1[q] = cc;
      Abuf[lq*4+q][h1w + 16*w + col] = f2bf(fast_sigm(acc1[3][q])*fast_tanh(cc));
    }
    __syncthreads();
  }

  // ---- swap weights to decoder ----
  #pragma unroll
  for (int i=0;i<4;i++){
    #pragma unroll
    for (int kb=0;kb<5;kb++) W0r[i][kb] = decW0[(size_t)(8*i+w)*320 + (size_t)kb*64 + l];
    #pragma unroll
    for (int kb=0;kb<8;kb++) W1r[i][kb] = decW1[(size_t)(8*i+w)*512 + (size_t)kb*64 + l];
    bs0[i] = biases[1024 + (8*i+w)*16 + col];
    bs1[i] = biases[1536 + (8*i+w)*16 + col];
  }
  short8 WLr[4];
  float blin = 0.f;
  if (w < 2){
    #pragma unroll
    for (int kb=0;kb<4;kb++) WLr[kb] = linT[(size_t)(w*4+kb)*64 + l];
    blin = biases[2048 + w*16 + col];
  }
  if (w == 0){
    *(short8*)&inpA[col][lq*8] = xf[(size_t)(T_-1)*64];   // dec input 0 = x[:,-1,:]
  }
  __syncthreads();

  // ---------------- decoder: 64 steps ----------------
  #pragma unroll 2
  for (int td = 0; td < TGT; td++){
    const int h0r = (td & 1) * 128;     // parity continues: 256+td has same parity as td
    const int h0w = 128 - h0r;
    const int h1r = 256 + h0r;
    const int h1w = 256 + h0w;

    // ---- phase 1: layer 0 ----
    short8 a0d = *(const short8*)&inpA[col][lq*8];
    short8 ah[4];
    #pragma unroll
    for (int kb=0;kb<4;kb++) ah[kb] = *(const short8*)&Abuf[col][h0r + kb*32 + lq*8];
    float4v acc0[4];
    #pragma unroll
    for (int i=0;i<4;i++){
      float4v a = {bs0[i],bs0[i],bs0[i],bs0[i]};
      a = MFMA_B16(a0d, W0r[i][0], a);
      #pragma unroll
      for (int kb=0;kb<4;kb++) a = MFMA_B16(ah[kb], W0r[i][kb+1], a);
      acc0[i] = a;
    }
    #pragma unroll
    for (int q=0;q<4;q++){
      float cc = fast_sigm(acc0[1][q])*c0[q] + fast_sigm(acc0[0][q])*fast_tanh(acc0[2][q]);
      c0[q] = cc;
      Abuf[lq*4+q][h0w + 16*w + col] = f2bf(fast_sigm(acc0[3][q])*fast_tanh(cc));
    }
    __syncthreads();

    // ---- phase 2: layer 1 ----
    short8 a1[8];
    #pragma unroll
    for (int kb=0;kb<4;kb++) a1[kb]   = *(const short8*)&Abuf[col][h0w + kb*32 + lq*8];
    #pragma unroll
    for (int kb=0;kb<4;kb++) a1[4+kb] = *(const short8*)&Abuf[col][h1r + kb*32 + lq*8];
    float4v acc1[4];
    #pragma unroll
    for (int i=0;i<4;i++){
      float4v a = {bs1[i],bs1[i],bs1[i],bs1[i]};
      #pragma unroll
      for (int kb=0;kb<8;kb++) a = MFMA_B16(a1[kb], W1r[i][kb], a);
      acc1[i] = a;
    }
    #pragma unroll
    for (int q=0;q<4;q++){
      float cc = fast_sigm(acc1[1][q])*c1[q] + fast_sigm(acc1[0][q])*fast_tanh(acc1[2][q]);
      c1[q] = cc;
      Abuf[lq*4+q][h1w + 16*w + col] = f2bf(fast_sigm(acc1[3][q])*fast_tanh(cc));
    }
    __syncthreads();

    // ---- phase 3: projection + feedback ----
    if (w < 2){
      short8 hf[4];
      #pragma unroll
      for (int kb=0;kb<4;kb++) hf[kb] = *(const short8*)&Abuf[col][h1w + kb*32 + lq*8];
      float4v a = {blin,blin,blin,blin};
      #pragma unroll
      for (int kb=0;kb<4;kb++) a = MFMA_B16(hf[kb], WLr[kb], a);
      #pragma unroll
      for (int q=0;q<4;q++){
        float v = a[q];
        int b = bblk*16 + lq*4 + q;
        out[((size_t)b*TGT + td)*DIN + (w*16 + col)] = v;
        inpA[lq*4+q][w*16 + col] = f2bf(v);
      }
    }
    __syncthreads();
  }
}

// ---------------- host ----------------
extern "C" void kernel_launch(void* const* d_in, const int* in_sizes, int n_in,
                              void* d_out, int out_size, void* d_ws, size_t ws_size,
                              hipStream_t stream) {
  const float* x      = (const float*)d_in[0];
  const float* eWih0  = (const float*)d_in[2];
  const float* eWhh0  = (const float*)d_in[3];
  const float* eb0a   = (const float*)d_in[4];
  const float* eb0b   = (const float*)d_in[5];
  const float* eWih1  = (const float*)d_in[6];
  const float* eWhh1  = (const float*)d_in[7];
  const float* eb1a   = (const float*)d_in[8];
  const float* eb1b   = (const float*)d_in[9];
  const float* dWih0  = (const float*)d_in[10];
  const float* dWhh0  = (const float*)d_in[11];
  const float* db0a   = (const float*)d_in[12];
  const float* db0b   = (const float*)d_in[13];
  const float* dWih1  = (const float*)d_in[14];
  const float* dWhh1  = (const float*)d_in[15];
  const float* db1a   = (const float*)d_in[16];
  const float* db1b   = (const float*)d_in[17];
  const float* linW   = (const float*)d_in[18];
  const float* linb   = (const float*)d_in[19];

  char* ws = (char*)d_ws;
  short8* xfrag = (short8*)(ws + OFF_XFRAG);
  short8* encW0 = (short8*)(ws + OFF_EW0);
  short8* encW1 = (short8*)(ws + OFF_EW1);
  short8* decW0 = (short8*)(ws + OFF_DW0);
  short8* decW1 = (short8*)(ws + OFF_DW1);
  short8* linT  = (short8*)(ws + OFF_LIN);
  float*  biases= (float*)(ws + OFF_BIAS);

  prep_x_kernel<<<2048, 256, 0, stream>>>(x, xfrag);
  prep_w_kernel<<<219, 256, 0, stream>>>(
      eWih0,eWhh0,eWih1,eWhh1,dWih0,dWhh0,dWih1,dWhh1,linW,
      eb0a,eb0b,eb1a,eb1b,db0a,db0b,db1a,db1b,linb,
      encW0,encW1,decW0,decW1,linT,biases);
  lstm_main_kernel<<<32, 512, 0, stream>>>(
      xfrag, encW0, encW1, decW0, decW1, linT, biases, (float*)d_out);
}

// Round 5
// 745.785 us; speedup vs baseline: 2.6886x; 1.6222x over previous
//
#include <hip/hip_runtime.h>
#include <cstdint>
#include <cstddef>

typedef short  short8  __attribute__((ext_vector_type(8)));
typedef float  float4v __attribute__((ext_vector_type(4)));

#define MFMA_B16(a,b,c) __builtin_amdgcn_mfma_f32_16x16x32_bf16(a,b,c,0,0,0)

static constexpr int B_  = 512;
static constexpr int T_  = 256;
static constexpr int DIN = 32;
static constexpr int H_  = 128;
static constexpr int TGT = 64;

// ---- workspace layout (bytes) ----
static constexpr size_t OFF_XFRAG = 0;                          // 8,388,608
static constexpr size_t OFF_EW0   = 8388608;                    // 163,840
static constexpr size_t OFF_EW1LO = OFF_EW0   + 163840;         // 131,072 (kb 0..3)
static constexpr size_t OFF_EW1HI = OFF_EW1LO + 131072;         // 131,072 (kb 4..7)
static constexpr size_t OFF_DW0   = OFF_EW1HI + 131072;         // 163,840
static constexpr size_t OFF_DW1LO = OFF_DW0   + 163840;         // 131,072
static constexpr size_t OFF_DW1HI = OFF_DW1LO + 131072;         // 131,072
static constexpr size_t OFF_LIN   = OFF_DW1HI + 131072;         // 8,192
static constexpr size_t OFF_BIAS  = OFF_LIN   + 8192;           // 8,320
static constexpr size_t WS_NEED   = OFF_BIAS  + 8320;           // ~9.26 MB

// ---- dynamic LDS layout (bytes) ----
static constexpr int SM_W    = 0;          // short8 Wlds[8192]   = 131,072 (W1 hi-half)
static constexpr int SM_ABUF = 131072;     // short Abuf[16][520] = 16,640
static constexpr int SM_INP  = 147712;     // short inpA[16][40]  = 1,280
static constexpr int SM_LIN  = 148992;     // short8 Wlin[512]    = 8,192
static constexpr int SM_TOTAL= 157184;     // <= 163,840

__device__ __forceinline__ short f2bf(float f){
  unsigned u = __float_as_uint(f);
  unsigned r = (u + 0x7fffu + ((u>>16)&1u)) >> 16;   // RNE
  return (short)(r & 0xffffu);
}
__device__ __forceinline__ float fast_sigm(float x){
  float e = __expf(-x);
  return __builtin_amdgcn_rcpf(1.f + e);
}
__device__ __forceinline__ float fast_tanh(float x){
  float e = __expf(-2.f*x);                 // tanh = 2*sigm(2x)-1
  return __builtin_amdgcn_rcpf(1.f + e)*2.f - 1.f;
}

// ---------------- prep: x -> bf16 A-fragment tiles ----------------
__global__ void prep_x_kernel(const float* __restrict__ x, short8* __restrict__ xfrag){
  int i = blockIdx.x*256 + threadIdx.x;           // 32*256*64 entries
  if (i >= 32*256*64) return;
  int l    = i & 63;
  int t    = (i >> 6) & 255;
  int bblk = i >> 14;
  int b    = bblk*16 + (l & 15);
  const float* src = x + ((size_t)(b*T_ + t))*DIN + ((l>>4)*8);
  short8 v;
  #pragma unroll
  for (int j=0;j<8;j++) v[j] = f2bf(src[j]);
  xfrag[i] = v;
}

// ---------------- prep: weights -> bf16 B-fragment tiles ----------------
__device__ __forceinline__ void pack160(short8* __restrict__ dst,
                                        const float* __restrict__ Wih,   // (512,32)
                                        const float* __restrict__ Whh,   // (512,128)
                                        int e){
  int nt = e/320; int r = e%320; int kb = r/64; int l = r%64;
  int n  = nt*16 + (l&15);
  short8 v;
  #pragma unroll
  for (int j=0;j<8;j++){
    int k = kb*32 + (l>>4)*8 + j;
    float f = (k < 32) ? Wih[n*32 + k] : Whh[n*128 + (k-32)];
    v[j] = f2bf(f);
  }
  dst[e] = v;
}
// split variant: kb 0..3 -> lo array, kb 4..7 -> hi array
__device__ __forceinline__ void pack256s(short8* __restrict__ dlo, short8* __restrict__ dhi,
                                         const float* __restrict__ Wih,   // (512,128)
                                         const float* __restrict__ Whh,   // (512,128)
                                         int e){
  int nt = e/512; int r = e%512; int kb = r/64; int l = r%64;
  int n  = nt*16 + (l&15);
  short8 v;
  #pragma unroll
  for (int j=0;j<8;j++){
    int k = kb*32 + (l>>4)*8 + j;
    float f = (k < 128) ? Wih[n*128 + k] : Whh[n*128 + (k-128)];
    v[j] = f2bf(f);
  }
  if (kb < 4) dlo[(nt*4 + kb)*64 + l]     = v;
  else        dhi[(nt*4 + (kb-4))*64 + l] = v;
}

__global__ void prep_w_kernel(
    const float* __restrict__ eWih0, const float* __restrict__ eWhh0,
    const float* __restrict__ eWih1, const float* __restrict__ eWhh1,
    const float* __restrict__ dWih0, const float* __restrict__ dWhh0,
    const float* __restrict__ dWih1, const float* __restrict__ dWhh1,
    const float* __restrict__ linW,
    const float* __restrict__ eb0a, const float* __restrict__ eb0b,
    const float* __restrict__ eb1a, const float* __restrict__ eb1b,
    const float* __restrict__ db0a, const float* __restrict__ db0b,
    const float* __restrict__ db1a, const float* __restrict__ db1b,
    const float* __restrict__ linb,
    short8* __restrict__ encW0,
    short8* __restrict__ encW1lo, short8* __restrict__ encW1hi,
    short8* __restrict__ decW0,
    short8* __restrict__ decW1lo, short8* __restrict__ decW1hi,
    short8* __restrict__ linT,  float* __restrict__ biases)
{
  int i = blockIdx.x*256 + threadIdx.x;
  if (i < 10240)       { pack160(encW0, eWih0, eWhh0, i); }
  else if (i < 26624)  { pack256s(encW1lo, encW1hi, eWih1, eWhh1, i-10240); }
  else if (i < 36864)  { pack160(decW0, dWih0, dWhh0, i-26624); }
  else if (i < 53248)  { pack256s(decW1lo, decW1hi, dWih1, dWhh1, i-36864); }
  else if (i < 53760)  {
    int e = i - 53248;                       // lin: 2nt * 4kb * 64
    int nt = e/256; int r = e%256; int kb = r/64; int l = r%64;
    int n = nt*16 + (l&15);
    short8 v;
    #pragma unroll
    for (int j=0;j<8;j++){
      int k = kb*32 + (l>>4)*8 + j;          // k < 128
      v[j] = f2bf(linW[n*128 + k]);
    }
    linT[e] = v;
  }
  else if (i < 55840)  {
    int e = i - 53760;                       // 2080 bias entries
    float v;
    if      (e < 512)  v = eb0a[e]       + eb0b[e];
    else if (e < 1024) v = eb1a[e-512]   + eb1b[e-512];
    else if (e < 1536) v = db0a[e-1024]  + db0b[e-1024];
    else if (e < 2048) v = db1a[e-1536]  + db1b[e-1536];
    else               v = linb[e-2048];
    biases[e] = v;
  }
}

// ---------------- main fused persistent kernel ----------------
// 32 blocks (16 batch rows each) x 512 threads (8 waves).
// Wave w owns gate n-tiles {w, 8+w, 16+w, 24+w} = i,f,g,o gates of hidden
// slice [16w,16w+16) -> activations consume the wave's OWN accumulators.
// Register budget fix (R2/R4 spilled ~72 regs): W1's h1-half (128 KB) and
// the projection weights live in LDS, cutting per-wave weight regs from
// 208 -> 144. Weight ds_reads are constant-address, conflict-free, and
// have no barrier dependency -> pipelined behind the reg-weight MFMAs.
__global__ __launch_bounds__(512, 1) void lstm_main_kernel(
    const short8* __restrict__ xfrag,
    const short8* __restrict__ encW0,
    const short8* __restrict__ encW1lo, const short8* __restrict__ encW1hi,
    const short8* __restrict__ decW0,
    const short8* __restrict__ decW1lo, const short8* __restrict__ decW1hi,
    const short8* __restrict__ linT,  const float* __restrict__ biases,
    float* __restrict__ out)
{
  extern __shared__ __align__(16) char smem[];
  short8* Wlds        = (short8*)(smem + SM_W);
  short (*Abuf)[520]  = (short(*)[520])(smem + SM_ABUF);
  short (*inpA)[40]   = (short(*)[40])(smem + SM_INP);
  short8* Wlin        = (short8*)(smem + SM_LIN);

  const int tid  = threadIdx.x;
  const int w    = tid >> 6;
  const int l    = tid & 63;
  const int col  = l & 15;      // MFMA n (B,D) lane field / A m field
  const int lq   = l >> 4;
  const int bblk = blockIdx.x;

  // stage W1 hi-half (h1 part) into LDS + zero h state
  for (int i = tid; i < 8192; i += 512) Wlds[i] = encW1hi[i];
  for (int i = tid; i < 16*520; i += 512) ((short*)Abuf)[i] = 0;

  // ---- persistent weight registers (encoder first) ----
  short8 W0r[4][5];    // L0: n-tile 8i+w, kb<5  (k: 32 input + 128 h)
  short8 W1lo[4][4];   // L1 lo: n-tile 8i+w, kb<4 (k: 128 h0)
  #pragma unroll
  for (int i=0;i<4;i++){
    #pragma unroll
    for (int kb=0;kb<5;kb++) W0r[i][kb]  = encW0  [(size_t)(8*i+w)*320 + (size_t)kb*64 + l];
    #pragma unroll
    for (int kb=0;kb<4;kb++) W1lo[i][kb] = encW1lo[(size_t)(8*i+w)*256 + (size_t)kb*64 + l];
  }
  float bs0[4], bs1[4];
  #pragma unroll
  for (int i=0;i<4;i++){
    bs0[i] = biases[       (8*i+w)*16 + col];
    bs1[i] = biases[512 +  (8*i+w)*16 + col];
  }

  float c0[4] = {0.f,0.f,0.f,0.f};
  float c1[4] = {0.f,0.f,0.f,0.f};

  const short8* xf = xfrag + (size_t)bblk*T_*64 + l;
  short8 a0 = xf[0];
  __syncthreads();

  // ---------------- encoder: 256 steps ----------------
  #pragma unroll 2
  for (int t = 0; t < T_; t++){
    const int h0r = (t & 1) * 128;
    const int h0w = 128 - h0r;
    const int h1r = 256 + h0r;
    const int h1w = 256 + h0w;

    // ---- phase 1: layer 0 ----
    short8 ah[4];
    #pragma unroll
    for (int kb=0;kb<4;kb++) ah[kb] = *(const short8*)&Abuf[col][h0r + kb*32 + lq*8];
    float4v acc0[4];
    #pragma unroll
    for (int i=0;i<4;i++){
      float4v a = {bs0[i],bs0[i],bs0[i],bs0[i]};
      a = MFMA_B16(a0, W0r[i][0], a);
      #pragma unroll
      for (int kb=0;kb<4;kb++) a = MFMA_B16(ah[kb], W0r[i][kb+1], a);
      acc0[i] = a;
    }
    short8 a0n = xf[(size_t)((t+1 < T_) ? t+1 : t)*64];   // prefetch next frame
    #pragma unroll
    for (int q=0;q<4;q++){
      float cc = fast_sigm(acc0[1][q])*c0[q] + fast_sigm(acc0[0][q])*fast_tanh(acc0[2][q]);
      c0[q] = cc;
      Abuf[lq*4+q][h0w + 16*w + col] = f2bf(fast_sigm(acc0[3][q])*fast_tanh(cc));
    }
    a0 = a0n;
    __syncthreads();

    // ---- phase 2: layer 1 ----
    short8 a1lo[4], a1hi[4];
    #pragma unroll
    for (int kb=0;kb<4;kb++) a1lo[kb] = *(const short8*)&Abuf[col][h0w + kb*32 + lq*8];
    #pragma unroll
    for (int kb=0;kb<4;kb++) a1hi[kb] = *(const short8*)&Abuf[col][h1r + kb*32 + lq*8];
    float4v acc1[4];
    #pragma unroll
    for (int i=0;i<4;i++){
      float4v a = {bs1[i],bs1[i],bs1[i],bs1[i]};
      #pragma unroll
      for (int kb=0;kb<4;kb++) a = MFMA_B16(a1lo[kb], W1lo[i][kb], a);
      #pragma unroll
      for (int kb=0;kb<4;kb++){
        short8 wv = Wlds[((8*i+w)*4 + kb)*64 + l];
        a = MFMA_B16(a1hi[kb], wv, a);
      }
      acc1[i] = a;
    }
    #pragma unroll
    for (int q=0;q<4;q++){
      float cc = fast_sigm(acc1[1][q])*c1[q] + fast_sigm(acc1[0][q])*fast_tanh(acc1[2][q]);
      c1[q] = cc;
      Abuf[lq*4+q][h1w + 16*w + col] = f2bf(fast_sigm(acc1[3][q])*fast_tanh(cc));
    }
    __syncthreads();
  }

  // ---- swap weights to decoder ----
  for (int i = tid; i < 8192; i += 512) Wlds[i] = decW1hi[i];   // safe: all enc reads done
  if (tid < 512) Wlin[tid] = linT[tid];
  #pragma unroll
  for (int i=0;i<4;i++){
    #pragma unroll
    for (int kb=0;kb<5;kb++) W0r[i][kb]  = decW0  [(size_t)(8*i+w)*320 + (size_t)kb*64 + l];
    #pragma unroll
    for (int kb=0;kb<4;kb++) W1lo[i][kb] = decW1lo[(size_t)(8*i+w)*256 + (size_t)kb*64 + l];
    bs0[i] = biases[1024 + (8*i+w)*16 + col];
    bs1[i] = biases[1536 + (8*i+w)*16 + col];
  }
  float blin = (w < 2) ? biases[2048 + w*16 + col] : 0.f;
  if (w == 0){
    *(short8*)&inpA[col][lq*8] = xf[(size_t)(T_-1)*64];   // dec input 0 = x[:,-1,:]
  }
  __syncthreads();

  // ---------------- decoder: 64 steps ----------------
  #pragma unroll 2
  for (int td = 0; td < TGT; td++){
    const int h0r = (td & 1) * 128;     // parity continues: 256+td has same parity as td
    const int h0w = 128 - h0r;
    const int h1r = 256 + h0r;
    const int h1w = 256 + h0w;

    // ---- phase 1: layer 0 ----
    short8 a0d = *(const short8*)&inpA[col][lq*8];
    short8 ah[4];
    #pragma unroll
    for (int kb=0;kb<4;kb++) ah[kb] = *(const short8*)&Abuf[col][h0r + kb*32 + lq*8];
    float4v acc0[4];
    #pragma unroll
    for (int i=0;i<4;i++){
      float4v a = {bs0[i],bs0[i],bs0[i],bs0[i]};
      a = MFMA_B16(a0d, W0r[i][0], a);
      #pragma unroll
      for (int kb=0;kb<4;kb++) a = MFMA_B16(ah[kb], W0r[i][kb+1], a);
      acc0[i] = a;
    }
    #pragma unroll
    for (int q=0;q<4;q++){
      float cc = fast_sigm(acc0[1][q])*c0[q] + fast_sigm(acc0[0][q])*fast_tanh(acc0[2][q]);
      c0[q] = cc;
      Abuf[lq*4+q][h0w + 16*w + col] = f2bf(fast_sigm(acc0[3][q])*fast_tanh(cc));
    }
    __syncthreads();

    // ---- phase 2: layer 1 ----
    short8 a1lo[4], a1hi[4];
    #pragma unroll
    for (int kb=0;kb<4;kb++) a1lo[kb] = *(const short8*)&Abuf[col][h0w + kb*32 + lq*8];
    #pragma unroll
    for (int kb=0;kb<4;kb++) a1hi[kb] = *(const short8*)&Abuf[col][h1r + kb*32 + lq*8];
    float4v acc1[4];
    #pragma unroll
    for (int i=0;i<4;i++){
      float4v a = {bs1[i],bs1[i],bs1[i],bs1[i]};
      #pragma unroll
      for (int kb=0;kb<4;kb++) a = MFMA_B16(a1lo[kb], W1lo[i][kb], a);
      #pragma unroll
      for (int kb=0;kb<4;kb++){
        short8 wv = Wlds[((8*i+w)*4 + kb)*64 + l];
        a = MFMA_B16(a1hi[kb], wv, a);
      }
      acc1[i] = a;
    }
    #pragma unroll
    for (int q=0;q<4;q++){
      float cc = fast_sigm(acc1[1][q])*c1[q] + fast_sigm(acc1[0][q])*fast_tanh(acc1[2][q]);
      c1[q] = cc;
      Abuf[lq*4+q][h1w + 16*w + col] = f2bf(fast_sigm(acc1[3][q])*fast_tanh(cc));
    }
    __syncthreads();

    // ---- phase 3: projection + feedback ----
    if (w < 2){
      short8 hf[4];
      #pragma unroll
      for (int kb=0;kb<4;kb++) hf[kb] = *(const short8*)&Abuf[col][h1w + kb*32 + lq*8];
      float4v a = {blin,blin,blin,blin};
      #pragma unroll
      for (int kb=0;kb<4;kb++){
        short8 wv = Wlin[(w*4+kb)*64 + l];
        a = MFMA_B16(hf[kb], wv, a);
      }
      #pragma unroll
      for (int q=0;q<4;q++){
        float v = a[q];
        int b = bblk*16 + lq*4 + q;
        out[((size_t)b*TGT + td)*DIN + (w*16 + col)] = v;
        inpA[lq*4+q][w*16 + col] = f2bf(v);
      }
    }
    __syncthreads();
  }
}

// ---------------- host ----------------
extern "C" void kernel_launch(void* const* d_in, const int* in_sizes, int n_in,
                              void* d_out, int out_size, void* d_ws, size_t ws_size,
                              hipStream_t stream) {
  const float* x      = (const float*)d_in[0];
  const float* eWih0  = (const float*)d_in[2];
  const float* eWhh0  = (const float*)d_in[3];
  const float* eb0a   = (const float*)d_in[4];
  const float* eb0b   = (const float*)d_in[5];
  const float* eWih1  = (const float*)d_in[6];
  const float* eWhh1  = (const float*)d_in[7];
  const float* eb1a   = (const float*)d_in[8];
  const float* eb1b   = (const float*)d_in[9];
  const float* dWih0  = (const float*)d_in[10];
  const float* dWhh0  = (const float*)d_in[11];
  const float* db0a   = (const float*)d_in[12];
  const float* db0b   = (const float*)d_in[13];
  const float* dWih1  = (const float*)d_in[14];
  const float* dWhh1  = (const float*)d_in[15];
  const float* db1a   = (const float*)d_in[16];
  const float* db1b   = (const float*)d_in[17];
  const float* linW   = (const float*)d_in[18];
  const float* linb   = (const float*)d_in[19];

  char* ws = (char*)d_ws;
  short8* xfrag   = (short8*)(ws + OFF_XFRAG);
  short8* encW0   = (short8*)(ws + OFF_EW0);
  short8* encW1lo = (short8*)(ws + OFF_EW1LO);
  short8* encW1hi = (short8*)(ws + OFF_EW1HI);
  short8* decW0   = (short8*)(ws + OFF_DW0);
  short8* decW1lo = (short8*)(ws + OFF_DW1LO);
  short8* decW1hi = (short8*)(ws + OFF_DW1HI);
  short8* linT    = (short8*)(ws + OFF_LIN);
  float*  biases  = (float*)(ws + OFF_BIAS);

  // allow >64 KB dynamic LDS (host-side attribute, graph-capture safe)
  hipFuncSetAttribute((const void*)lstm_main_kernel,
                      hipFuncAttributeMaxDynamicSharedMemorySize, SM_TOTAL);

  prep_x_kernel<<<2048, 256, 0, stream>>>(x, xfrag);
  prep_w_kernel<<<219, 256, 0, stream>>>(
      eWih0,eWhh0,eWih1,eWhh1,dWih0,dWhh0,dWih1,dWhh1,linW,
      eb0a,eb0b,eb1a,eb1b,db0a,db0b,db1a,db1b,linb,
      encW0,encW1lo,encW1hi,decW0,decW1lo,decW1hi,linT,biases);
  lstm_main_kernel<<<32, 512, SM_TOTAL, stream>>>(
      xfrag, encW0, encW1lo, encW1hi, decW0, decW1lo, decW1hi,
      linT, biases, (float*)d_out);
}

// Round 6
// 736.617 us; speedup vs baseline: 2.7220x; 1.0124x over previous
//
#include <hip/hip_runtime.h>
#include <cstdint>
#include <cstddef>

typedef short  short8  __attribute__((ext_vector_type(8)));
typedef float  float4v __attribute__((ext_vector_type(4)));

#define MFMA_B16(a,b,c) __builtin_amdgcn_mfma_f32_16x16x32_bf16(a,b,c,0,0,0)

static constexpr int B_  = 512;
static constexpr int T_  = 256;
static constexpr int DIN = 32;
static constexpr int H_  = 128;
static constexpr int TGT = 64;

// ---- workspace layout (bytes) ----
static constexpr size_t OFF_XFRAG = 0;                          // 8,388,608
static constexpr size_t OFF_EW0   = 8388608;                    // 163,840
static constexpr size_t OFF_EW1LO = OFF_EW0   + 163840;         // 131,072 (kb 0..3)
static constexpr size_t OFF_EW1HI = OFF_EW1LO + 131072;         // 131,072 (kb 4..7)
static constexpr size_t OFF_DW0   = OFF_EW1HI + 131072;         // 163,840
static constexpr size_t OFF_DW1LO = OFF_DW0   + 163840;         // 131,072
static constexpr size_t OFF_DW1HI = OFF_DW1LO + 131072;         // 131,072
static constexpr size_t OFF_LIN   = OFF_DW1HI + 131072;         // 8,192
static constexpr size_t OFF_BIAS  = OFF_LIN   + 8192;           // 8,320
static constexpr size_t WS_NEED   = OFF_BIAS  + 8320;           // ~9.26 MB

// ---- dynamic LDS layout (bytes) ----
static constexpr int SM_W    = 0;          // short8 Wlds[8192]   = 131,072 (W1 hi-half)
static constexpr int SM_ABUF = 131072;     // short Abuf[16][520] = 16,640
static constexpr int SM_INP  = 147712;     // short inpA[16][40]  = 1,280
static constexpr int SM_LIN  = 148992;     // short8 Wlin[512]    = 8,192
static constexpr int SM_TOTAL= 157184;     // <= 163,840

__device__ __forceinline__ short f2bf(float f){
  unsigned u = __float_as_uint(f);
  unsigned r = (u + 0x7fffu + ((u>>16)&1u)) >> 16;   // RNE
  return (short)(r & 0xffffu);
}
__device__ __forceinline__ float fast_sigm(float x){
  float e = __expf(-x);
  return __builtin_amdgcn_rcpf(1.f + e);
}
__device__ __forceinline__ float fast_tanh(float x){
  float e = __expf(-2.f*x);                 // tanh = 2*sigm(2x)-1
  return __builtin_amdgcn_rcpf(1.f + e)*2.f - 1.f;
}

// ---------------- prep: x -> bf16 A-fragment tiles ----------------
__global__ void prep_x_kernel(const float* __restrict__ x, short8* __restrict__ xfrag){
  int i = blockIdx.x*256 + threadIdx.x;           // 32*256*64 entries
  if (i >= 32*256*64) return;
  int l    = i & 63;
  int t    = (i >> 6) & 255;
  int bblk = i >> 14;
  int b    = bblk*16 + (l & 15);
  const float* src = x + ((size_t)(b*T_ + t))*DIN + ((l>>4)*8);
  short8 v;
  #pragma unroll
  for (int j=0;j<8;j++) v[j] = f2bf(src[j]);
  xfrag[i] = v;
}

// ---------------- prep: weights -> bf16 B-fragment tiles ----------------
__device__ __forceinline__ void pack160(short8* __restrict__ dst,
                                        const float* __restrict__ Wih,   // (512,32)
                                        const float* __restrict__ Whh,   // (512,128)
                                        int e){
  int nt = e/320; int r = e%320; int kb = r/64; int l = r%64;
  int n  = nt*16 + (l&15);
  short8 v;
  #pragma unroll
  for (int j=0;j<8;j++){
    int k = kb*32 + (l>>4)*8 + j;
    float f = (k < 32) ? Wih[n*32 + k] : Whh[n*128 + (k-32)];
    v[j] = f2bf(f);
  }
  dst[e] = v;
}
// split variant: kb 0..3 -> lo array, kb 4..7 -> hi array
__device__ __forceinline__ void pack256s(short8* __restrict__ dlo, short8* __restrict__ dhi,
                                         const float* __restrict__ Wih,   // (512,128)
                                         const float* __restrict__ Whh,   // (512,128)
                                         int e){
  int nt = e/512; int r = e%512; int kb = r/64; int l = r%64;
  int n  = nt*16 + (l&15);
  short8 v;
  #pragma unroll
  for (int j=0;j<8;j++){
    int k = kb*32 + (l>>4)*8 + j;
    float f = (k < 128) ? Wih[n*128 + k] : Whh[n*128 + (k-128)];
    v[j] = f2bf(f);
  }
  if (kb < 4) dlo[(nt*4 + kb)*64 + l]     = v;
  else        dhi[(nt*4 + (kb-4))*64 + l] = v;
}

__global__ void prep_w_kernel(
    const float* __restrict__ eWih0, const float* __restrict__ eWhh0,
    const float* __restrict__ eWih1, const float* __restrict__ eWhh1,
    const float* __restrict__ dWih0, const float* __restrict__ dWhh0,
    const float* __restrict__ dWih1, const float* __restrict__ dWhh1,
    const float* __restrict__ linW,
    const float* __restrict__ eb0a, const float* __restrict__ eb0b,
    const float* __restrict__ eb1a, const float* __restrict__ eb1b,
    const float* __restrict__ db0a, const float* __restrict__ db0b,
    const float* __restrict__ db1a, const float* __restrict__ db1b,
    const float* __restrict__ linb,
    short8* __restrict__ encW0,
    short8* __restrict__ encW1lo, short8* __restrict__ encW1hi,
    short8* __restrict__ decW0,
    short8* __restrict__ decW1lo, short8* __restrict__ decW1hi,
    short8* __restrict__ linT,  float* __restrict__ biases)
{
  int i = blockIdx.x*256 + threadIdx.x;
  if (i < 10240)       { pack160(encW0, eWih0, eWhh0, i); }
  else if (i < 26624)  { pack256s(encW1lo, encW1hi, eWih1, eWhh1, i-10240); }
  else if (i < 36864)  { pack160(decW0, dWih0, dWhh0, i-26624); }
  else if (i < 53248)  { pack256s(decW1lo, decW1hi, dWih1, dWhh1, i-36864); }
  else if (i < 53760)  {
    int e = i - 53248;                       // lin: 2nt * 4kb * 64
    int nt = e/256; int r = e%256; int kb = r/64; int l = r%64;
    int n = nt*16 + (l&15);
    short8 v;
    #pragma unroll
    for (int j=0;j<8;j++){
      int k = kb*32 + (l>>4)*8 + j;          // k < 128
      v[j] = f2bf(linW[n*128 + k]);
    }
    linT[e] = v;
  }
  else if (i < 55840)  {
    int e = i - 53760;                       // 2080 bias entries
    float v;
    if      (e < 512)  v = eb0a[e]       + eb0b[e];
    else if (e < 1024) v = eb1a[e-512]   + eb1b[e-512];
    else if (e < 1536) v = db0a[e-1024]  + db0b[e-1024];
    else if (e < 2048) v = db1a[e-1536]  + db1b[e-1536];
    else               v = linb[e-2048];
    biases[e] = v;
  }
}

// ---------------- main fused persistent kernel ----------------
// 32 blocks (16 batch rows each) x 512 threads (8 waves).
// Wave w owns gate n-tiles {w, 8+w, 16+w, 24+w} of each layer.
// Encoder is software-pipelined: one phase computes L0(i) AND L1(i-1)
// (both depend only on h0(i-1), h1(i-2)) -> 1 barrier/step, shared h0
// operand read, two independent MFMA->activation chains for ILP.
// Weight placement (R5): W0 + W1-lo in VGPRs, W1-hi + lin in LDS.
__global__ __launch_bounds__(512, 1) void lstm_main_kernel(
    const short8* __restrict__ xfrag,
    const short8* __restrict__ encW0,
    const short8* __restrict__ encW1lo, const short8* __restrict__ encW1hi,
    const short8* __restrict__ decW0,
    const short8* __restrict__ decW1lo, const short8* __restrict__ decW1hi,
    const short8* __restrict__ linT,  const float* __restrict__ biases,
    float* __restrict__ out)
{
  extern __shared__ __align__(16) char smem[];
  short8* Wlds        = (short8*)(smem + SM_W);
  short (*Abuf)[520]  = (short(*)[520])(smem + SM_ABUF);
  short (*inpA)[40]   = (short(*)[40])(smem + SM_INP);
  short8* Wlin        = (short8*)(smem + SM_LIN);

  const int tid  = threadIdx.x;
  const int w    = tid >> 6;
  const int l    = tid & 63;
  const int col  = l & 15;      // MFMA n (B,D) lane field / A m field
  const int lq   = l >> 4;
  const int bblk = blockIdx.x;

  // stage W1 hi-half (h1 part) into LDS + zero h state
  for (int i = tid; i < 8192; i += 512) Wlds[i] = encW1hi[i];
  for (int i = tid; i < 16*520; i += 512) ((short*)Abuf)[i] = 0;

  // ---- persistent weight registers (encoder first) ----
  short8 W0r[4][5];    // L0: n-tile 8i+w, kb<5  (k: 32 input + 128 h)
  short8 W1lo[4][4];   // L1 lo: n-tile 8i+w, kb<4 (k: 128 h0)
  #pragma unroll
  for (int i=0;i<4;i++){
    #pragma unroll
    for (int kb=0;kb<5;kb++) W0r[i][kb]  = encW0  [(size_t)(8*i+w)*320 + (size_t)kb*64 + l];
    #pragma unroll
    for (int kb=0;kb<4;kb++) W1lo[i][kb] = encW1lo[(size_t)(8*i+w)*256 + (size_t)kb*64 + l];
  }
  float bs0[4], bs1[4];
  #pragma unroll
  for (int i=0;i<4;i++){
    bs0[i] = biases[       (8*i+w)*16 + col];
    bs1[i] = biases[512 +  (8*i+w)*16 + col];
  }

  float c0[4] = {0.f,0.f,0.f,0.f};
  float c1[4] = {0.f,0.f,0.f,0.f};

  const short8* xf = xfrag + (size_t)bblk*T_*64 + l;
  short8 a0 = xf[0];
  __syncthreads();

  // ---------------- encoder: software-pipelined, 1 barrier/step ----------------
  // iter i (1..255): compute h0(i) [L0] and h1(i-1) [L1] in one phase.
  // h0(i) written at parity i&1; h1(j) written at parity j&1 (region +256).

  // ---- peel: i=0, L0 only ----
  {
    // h0(-1) = zeros at parity 1
    short8 hp[4];
    #pragma unroll
    for (int kb=0;kb<4;kb++) hp[kb] = *(const short8*)&Abuf[col][128 + kb*32 + lq*8];
    float4v acc0[4];
    #pragma unroll
    for (int i4=0;i4<4;i4++){
      float4v a = {bs0[i4],bs0[i4],bs0[i4],bs0[i4]};
      a = MFMA_B16(a0, W0r[i4][0], a);
      #pragma unroll
      for (int kb=0;kb<4;kb++) a = MFMA_B16(hp[kb], W0r[i4][kb+1], a);
      acc0[i4] = a;
    }
    a0 = xf[64];
    #pragma unroll
    for (int q=0;q<4;q++){
      float cc = fast_sigm(acc0[1][q])*c0[q] + fast_sigm(acc0[0][q])*fast_tanh(acc0[2][q]);
      c0[q] = cc;
      Abuf[lq*4+q][0 + 16*w + col] = f2bf(fast_sigm(acc0[3][q])*fast_tanh(cc));  // parity 0
    }
    __syncthreads();
  }

  // ---- main: i = 1..255 ----
  #pragma unroll 2
  for (int i = 1; i < T_; i++){
    const int p_h0_r = ((i-1)&1)*128;          // h0(i-1) — shared by L0 and L1
    const int p_h0_w = (i&1)*128;              // h0(i)
    const int p_h1_r = 256 + (i&1)*128;        // h1(i-2)
    const int p_h1_w = 256 + ((i-1)&1)*128;    // h1(i-1)

    short8 hp[4], h1p[4];
    #pragma unroll
    for (int kb=0;kb<4;kb++) hp[kb]  = *(const short8*)&Abuf[col][p_h0_r + kb*32 + lq*8];
    #pragma unroll
    for (int kb=0;kb<4;kb++) h1p[kb] = *(const short8*)&Abuf[col][p_h1_r + kb*32 + lq*8];

    float4v acc0[4], acc1[4];
    #pragma unroll
    for (int i4=0;i4<4;i4++){
      float4v a = {bs0[i4],bs0[i4],bs0[i4],bs0[i4]};
      a = MFMA_B16(a0, W0r[i4][0], a);
      #pragma unroll
      for (int kb=0;kb<4;kb++) a = MFMA_B16(hp[kb], W0r[i4][kb+1], a);
      acc0[i4] = a;

      float4v b = {bs1[i4],bs1[i4],bs1[i4],bs1[i4]};
      #pragma unroll
      for (int kb=0;kb<4;kb++) b = MFMA_B16(hp[kb], W1lo[i4][kb], b);
      #pragma unroll
      for (int kb=0;kb<4;kb++){
        short8 wv = Wlds[((8*i4+w)*4 + kb)*64 + l];
        b = MFMA_B16(h1p[kb], wv, b);
      }
      acc1[i4] = b;
    }
    a0 = xf[(size_t)((i+1 < T_) ? i+1 : i)*64];   // prefetch next frame

    #pragma unroll
    for (int q=0;q<4;q++){
      float cc = fast_sigm(acc0[1][q])*c0[q] + fast_sigm(acc0[0][q])*fast_tanh(acc0[2][q]);
      c0[q] = cc;
      Abuf[lq*4+q][p_h0_w + 16*w + col] = f2bf(fast_sigm(acc0[3][q])*fast_tanh(cc));
    }
    #pragma unroll
    for (int q=0;q<4;q++){
      float cc = fast_sigm(acc1[1][q])*c1[q] + fast_sigm(acc1[0][q])*fast_tanh(acc1[2][q]);
      c1[q] = cc;
      Abuf[lq*4+q][p_h1_w + 16*w + col] = f2bf(fast_sigm(acc1[3][q])*fast_tanh(cc));
    }
    __syncthreads();
  }

  // ---- epilogue: L1 for i-1 = 255 ----
  {
    const int p_h0_r = 128;        // h0(255), parity 1
    const int p_h1_r = 256 + 0;    // h1(254), parity 0
    const int p_h1_w = 256 + 128;  // h1(255), parity 1
    short8 hp[4], h1p[4];
    #pragma unroll
    for (int kb=0;kb<4;kb++) hp[kb]  = *(const short8*)&Abuf[col][p_h0_r + kb*32 + lq*8];
    #pragma unroll
    for (int kb=0;kb<4;kb++) h1p[kb] = *(const short8*)&Abuf[col][p_h1_r + kb*32 + lq*8];
    float4v acc1[4];
    #pragma unroll
    for (int i4=0;i4<4;i4++){
      float4v b = {bs1[i4],bs1[i4],bs1[i4],bs1[i4]};
      #pragma unroll
      for (int kb=0;kb<4;kb++) b = MFMA_B16(hp[kb], W1lo[i4][kb], b);
      #pragma unroll
      for (int kb=0;kb<4;kb++){
        short8 wv = Wlds[((8*i4+w)*4 + kb)*64 + l];
        b = MFMA_B16(h1p[kb], wv, b);
      }
      acc1[i4] = b;
    }
    #pragma unroll
    for (int q=0;q<4;q++){
      float cc = fast_sigm(acc1[1][q])*c1[q] + fast_sigm(acc1[0][q])*fast_tanh(acc1[2][q]);
      c1[q] = cc;
      Abuf[lq*4+q][p_h1_w + 16*w + col] = f2bf(fast_sigm(acc1[3][q])*fast_tanh(cc));
    }
    __syncthreads();   // all encoder Wlds reads done before restage
  }

  // ---- swap weights to decoder ----
  for (int i = tid; i < 8192; i += 512) Wlds[i] = decW1hi[i];
  if (tid < 512) Wlin[tid] = linT[tid];
  #pragma unroll
  for (int i=0;i<4;i++){
    #pragma unroll
    for (int kb=0;kb<5;kb++) W0r[i][kb]  = decW0  [(size_t)(8*i+w)*320 + (size_t)kb*64 + l];
    #pragma unroll
    for (int kb=0;kb<4;kb++) W1lo[i][kb] = decW1lo[(size_t)(8*i+w)*256 + (size_t)kb*64 + l];
    bs0[i] = biases[1024 + (8*i+w)*16 + col];
    bs1[i] = biases[1536 + (8*i+w)*16 + col];
  }
  float blin = (w < 2) ? biases[2048 + w*16 + col] : 0.f;
  if (w == 0){
    *(short8*)&inpA[col][lq*8] = xf[(size_t)(T_-1)*64];   // dec input 0 = x[:,-1,:]
  }
  __syncthreads();

  // ---------------- decoder: 64 steps, 3 phases ----------------
  // enc left h0/h1 at parity 1 -> dec td reads parity (td+1)&1, writes td&1.
  #pragma unroll 2
  for (int td = 0; td < TGT; td++){
    const int h0r = ((td+1)&1) * 128;
    const int h0w = 128 - h0r;
    const int h1r = 256 + h0r;
    const int h1w = 256 + h0w;

    // ---- phase 1: layer 0 ----
    short8 a0d = *(const short8*)&inpA[col][lq*8];
    short8 ah[4];
    #pragma unroll
    for (int kb=0;kb<4;kb++) ah[kb] = *(const short8*)&Abuf[col][h0r + kb*32 + lq*8];
    float4v acc0[4];
    #pragma unroll
    for (int i=0;i<4;i++){
      float4v a = {bs0[i],bs0[i],bs0[i],bs0[i]};
      a = MFMA_B16(a0d, W0r[i][0], a);
      #pragma unroll
      for (int kb=0;kb<4;kb++) a = MFMA_B16(ah[kb], W0r[i][kb+1], a);
      acc0[i] = a;
    }
    #pragma unroll
    for (int q=0;q<4;q++){
      float cc = fast_sigm(acc0[1][q])*c0[q] + fast_sigm(acc0[0][q])*fast_tanh(acc0[2][q]);
      c0[q] = cc;
      Abuf[lq*4+q][h0w + 16*w + col] = f2bf(fast_sigm(acc0[3][q])*fast_tanh(cc));
    }
    __syncthreads();

    // ---- phase 2: layer 1 ----
    short8 a1lo[4], a1hi[4];
    #pragma unroll
    for (int kb=0;kb<4;kb++) a1lo[kb] = *(const short8*)&Abuf[col][h0w + kb*32 + lq*8];
    #pragma unroll
    for (int kb=0;kb<4;kb++) a1hi[kb] = *(const short8*)&Abuf[col][h1r + kb*32 + lq*8];
    float4v acc1[4];
    #pragma unroll
    for (int i=0;i<4;i++){
      float4v a = {bs1[i],bs1[i],bs1[i],bs1[i]};
      #pragma unroll
      for (int kb=0;kb<4;kb++) a = MFMA_B16(a1lo[kb], W1lo[i][kb], a);
      #pragma unroll
      for (int kb=0;kb<4;kb++){
        short8 wv = Wlds[((8*i+w)*4 + kb)*64 + l];
        a = MFMA_B16(a1hi[kb], wv, a);
      }
      acc1[i] = a;
    }
    #pragma unroll
    for (int q=0;q<4;q++){
      float cc = fast_sigm(acc1[1][q])*c1[q] + fast_sigm(acc1[0][q])*fast_tanh(acc1[2][q]);
      c1[q] = cc;
      Abuf[lq*4+q][h1w + 16*w + col] = f2bf(fast_sigm(acc1[3][q])*fast_tanh(cc));
    }
    __syncthreads();

    // ---- phase 3: projection + feedback ----
    if (w < 2){
      short8 hf[4];
      #pragma unroll
      for (int kb=0;kb<4;kb++) hf[kb] = *(const short8*)&Abuf[col][h1w + kb*32 + lq*8];
      float4v a = {blin,blin,blin,blin};
      #pragma unroll
      for (int kb=0;kb<4;kb++){
        short8 wv = Wlin[(w*4+kb)*64 + l];
        a = MFMA_B16(hf[kb], wv, a);
      }
      #pragma unroll
      for (int q=0;q<4;q++){
        float v = a[q];
        int b = bblk*16 + lq*4 + q;
        out[((size_t)b*TGT + td)*DIN + (w*16 + col)] = v;
        inpA[lq*4+q][w*16 + col] = f2bf(v);
      }
    }
    __syncthreads();
  }
}

// ---------------- host ----------------
extern "C" void kernel_launch(void* const* d_in, const int* in_sizes, int n_in,
                              void* d_out, int out_size, void* d_ws, size_t ws_size,
                              hipStream_t stream) {
  const float* x      = (const float*)d_in[0];
  const float* eWih0  = (const float*)d_in[2];
  const float* eWhh0  = (const float*)d_in[3];
  const float* eb0a   = (const float*)d_in[4];
  const float* eb0b   = (const float*)d_in[5];
  const float* eWih1  = (const float*)d_in[6];
  const float* eWhh1  = (const float*)d_in[7];
  const float* eb1a   = (const float*)d_in[8];
  const float* eb1b   = (const float*)d_in[9];
  const float* dWih0  = (const float*)d_in[10];
  const float* dWhh0  = (const float*)d_in[11];
  const float* db0a   = (const float*)d_in[12];
  const float* db0b   = (const float*)d_in[13];
  const float* dWih1  = (const float*)d_in[14];
  const float* dWhh1  = (const float*)d_in[15];
  const float* db1a   = (const float*)d_in[16];
  const float* db1b   = (const float*)d_in[17];
  const float* linW   = (const float*)d_in[18];
  const float* linb   = (const float*)d_in[19];

  char* ws = (char*)d_ws;
  short8* xfrag   = (short8*)(ws + OFF_XFRAG);
  short8* encW0   = (short8*)(ws + OFF_EW0);
  short8* encW1lo = (short8*)(ws + OFF_EW1LO);
  short8* encW1hi = (short8*)(ws + OFF_EW1HI);
  short8* decW0   = (short8*)(ws + OFF_DW0);
  short8* decW1lo = (short8*)(ws + OFF_DW1LO);
  short8* decW1hi = (short8*)(ws + OFF_DW1HI);
  short8* linT    = (short8*)(ws + OFF_LIN);
  float*  biases  = (float*)(ws + OFF_BIAS);

  // allow >64 KB dynamic LDS (host-side attribute, graph-capture safe)
  hipFuncSetAttribute((const void*)lstm_main_kernel,
                      hipFuncAttributeMaxDynamicSharedMemorySize, SM_TOTAL);

  prep_x_kernel<<<2048, 256, 0, stream>>>(x, xfrag);
  prep_w_kernel<<<219, 256, 0, stream>>>(
      eWih0,eWhh0,eWih1,eWhh1,dWih0,dWhh0,dWih1,dWhh1,linW,
      eb0a,eb0b,eb1a,eb1b,db0a,db0b,db1a,db1b,linb,
      encW0,encW1lo,encW1hi,decW0,decW1lo,decW1hi,linT,biases);
  lstm_main_kernel<<<32, 512, SM_TOTAL, stream>>>(
      xfrag, encW0, encW1lo, encW1hi, decW0, decW1lo, decW1hi,
      linT, biases, (float*)d_out);
}